// Round 14
// baseline (72.769 us; speedup 1.0000x reference)
//
#include <hip/hip_runtime.h>
#include <math.h>

#define BATCH 8
#define NN 2048
#define FIN 256
#define FOUT 64
#define ALPHA 0.2f
#define RING 4

typedef __attribute__((ext_vector_type(8))) short bf16x8;
typedef __attribute__((ext_vector_type(4))) float f32x4;

static __device__ __forceinline__ unsigned short f2bf(float f) {
  unsigned int u = __float_as_uint(f);
  u += 0x7fffu + ((u >> 16) & 1u);
  return (unsigned short)(u >> 16);
}
static __device__ __forceinline__ float bf2f(unsigned short h) {
  return __uint_as_float(((unsigned int)h) << 16);
}
static __device__ __forceinline__ void gload16(const void* g, void* l) {
  __builtin_amdgcn_global_load_lds(
      (const __attribute__((address_space(1))) unsigned int*)g,
      (__attribute__((address_space(3))) unsigned int*)l, 16, 0, 0);
}

// ---------------------------------------------------------------------------
// K1: h = x@W via MFMA (hi/lo bf16 split), el/er, pre-swizzled h image.
// Unchanged numerics; + XCD swizzle so batch b's image is built on XCD b
// (matches K2's consumer locality).
// ---------------------------------------------------------------------------
__global__ __launch_bounds__(256) void k1_h(
    const float* __restrict__ x, const float* __restrict__ W,
    const float* __restrict__ a, float* __restrict__ el,
    float* __restrict__ er, unsigned char* __restrict__ hS) {
  __shared__ __align__(16) unsigned short lds[32768];  // 64 KB
  const int t = threadIdx.x;
  const int wv = t >> 6;
  const int l = t & 63;
  const int l15 = l & 15;
  const int kg = l >> 4;
  const int swz = (blockIdx.x & 7) * 32 + (blockIdx.x >> 3);  // XCD-bijective

  {
    const float4* W4 = (const float4*)W;
    #pragma unroll
    for (int i = 0; i < 16; ++i) {
      int f = t + i * 256;
      float4 v = W4[f];
      int k = f >> 4;
      int ob = (f & 15) * 4;
      float vv[4] = {v.x, v.y, v.z, v.w};
      #pragma unroll
      for (int c = 0; c < 4; ++c) {
        int o = ob + c;
        unsigned short hi = f2bf(vv[c]);
        unsigned short lo = f2bf(vv[c] - bf2f(hi));
        int idx = o * 256 + (((k >> 3) ^ (o & 7)) * 8) + (k & 7);
        lds[idx] = hi;
        lds[16384 + idx] = lo;
      }
    }
  }
  __syncthreads();

  const int row = swz * 64 + wv * 16 + l15;
  f32x4 acc[4] = {{0.f,0.f,0.f,0.f},{0.f,0.f,0.f,0.f},
                  {0.f,0.f,0.f,0.f},{0.f,0.f,0.f,0.f}};
  const float* xrow = x + (size_t)row * FIN;

  #pragma unroll
  for (int ks = 0; ks < 8; ++ks) {
    int k0 = ks * 32;
    float4 xa = *(const float4*)(xrow + k0 + kg * 8);
    float4 xb = *(const float4*)(xrow + k0 + kg * 8 + 4);
    float xv[8] = {xa.x, xa.y, xa.z, xa.w, xb.x, xb.y, xb.z, xb.w};
    bf16x8 ahi, alo;
    #pragma unroll
    for (int j = 0; j < 8; ++j) {
      unsigned short hi = f2bf(xv[j]);
      unsigned short lo = f2bf(xv[j] - bf2f(hi));
      ahi[j] = (short)hi;
      alo[j] = (short)lo;
    }
    int kgidx = ks * 4 + kg;
    #pragma unroll
    for (int ot = 0; ot < 4; ++ot) {
      int o = ot * 16 + l15;
      int base = o * 256 + ((kgidx ^ (o & 7)) * 8);
      bf16x8 bhi = *(const bf16x8*)&lds[base];
      bf16x8 blo = *(const bf16x8*)&lds[16384 + base];
      acc[ot] = __builtin_amdgcn_mfma_f32_16x16x32_bf16(ahi, bhi, acc[ot], 0, 0, 0);
      acc[ot] = __builtin_amdgcn_mfma_f32_16x16x32_bf16(ahi, blo, acc[ot], 0, 0, 0);
      acc[ot] = __builtin_amdgcn_mfma_f32_16x16x32_bf16(alo, bhi, acc[ot], 0, 0, 0);
    }
  }

  float aLv[4], aRv[4];
  #pragma unroll
  for (int ot = 0; ot < 4; ++ot) {
    aLv[ot] = a[ot * 16 + l15];
    aRv[ot] = a[64 + ot * 16 + l15];
  }
  #pragma unroll
  for (int jj = 0; jj < 4; ++jj) {
    float pl = 0.f, pr = 0.f;
    #pragma unroll
    for (int ot = 0; ot < 4; ++ot) {
      pl += acc[ot][jj] * aLv[ot];
      pr += acc[ot][jj] * aRv[ot];
    }
    #pragma unroll
    for (int s = 1; s < 16; s <<= 1) {
      pl += __shfl_xor(pl, s);
      pr += __shfl_xor(pr, s);
    }
    if (l15 == 0) {
      int grow = swz * 64 + wv * 16 + kg * 4 + jj;
      el[grow] = pl;
      er[grow] = pr;
    }
  }

  __syncthreads();
  #pragma unroll
  for (int ot = 0; ot < 4; ++ot) {
    int o = ot * 16 + l15;
    int xorv = (o >> 1) & 3;
    #pragma unroll
    for (int jj = 0; jj < 4; ++jj) {
      int m_loc = wv * 16 + kg * 4 + jj;
      int ks2 = m_loc >> 5;
      int kg2 = (m_loc >> 3) & 3;
      int j = m_loc & 7;
      int kgp = kg2 ^ xorv;
      float v = acc[ot][jj];
      unsigned short hi = f2bf(v);
      unsigned short lo = f2bf(v - bf2f(hi));
      int base = ((ks2 * 2 + 0) * 64 + o) * 32 + kgp * 8 + j;
      lds[base] = hi;
      lds[base + 2048] = lo;
    }
  }
  __syncthreads();

  {
    const uint4* src = (const uint4*)(const void*)lds;
    uint4* dst = (uint4*)(hS + (size_t)swz * 16384);
    #pragma unroll
    for (int i = 0; i < 4; ++i) dst[t + i * 256] = src[t + i * 256];
  }
}

// ---------------------------------------------------------------------------
// K2: producer-consumer wave specialization. 512 blocks x 192 thr.
// Block = 32 rows, sweeps ALL m (64 chunks of 32). Wave 2 = PRODUCER:
// streams adj -> 4-slot LDS ring (its vmem queue holds ONLY adj; counted
// vmcnt(8), never drained; fill retires 2 iters (~1600cyc) before use).
// Waves 0,1 = CONSUMERS (16 full rows each -> NO cross-wave combine):
// adj from ring via ds_read (lgkm queue), h-frags + er direct from L2
// (their vmem queue has NO HBM loads -> no in-order retirement coupling).
// One raw s_barrier per chunk. Ring XOR-swizzled via pre-swizzled global
// source (linear gload_lds dest), so consumer ds_read_b128 is 2-way (free).
// ---------------------------------------------------------------------------
__global__ __launch_bounds__(192, 2) void k2_attn(
    const int* __restrict__ adj, const unsigned char* __restrict__ hS,
    const float* __restrict__ el, const float* __restrict__ er,
    float* __restrict__ out) {
  __shared__ __align__(1024) unsigned char ring[RING][32][128];  // 16 KB
  const int t = threadIdx.x;
  const int wv = t / 64;
  const int l = t & 63;
  const int l15 = l & 15;
  const int kg = l >> 4;

  // XCD-bijective swizzle: 512 blocks, 64/XCD -> each XCD owns one batch
  int bid = blockIdx.x;
  int swz = (bid & 7) * 64 + (bid >> 3);
  int b = swz >> 6;
  int nb = (swz & 63) * 32;           // block's 32-row base within batch

  const size_t adjBase = (size_t)b * NN * NN + (size_t)nb * NN;  // ints

  if (wv == 2) {
    // ---------------- producer ----------------
    const int r8 = l >> 3;            // row-within-8-group
    const int u  = l & 7;             // 16B unit within 128B row segment
#define FILL(cc) {                                                          \
      int slot_ = (cc) & (RING - 1);                                        \
      _Pragma("unroll")                                                     \
      for (int i_ = 0; i_ < 4; ++i_) {                                      \
        int r_ = i_ * 8 + r8;                                               \
        const unsigned char* src_ = (const unsigned char*)adj               \
            + (adjBase + (size_t)r_ * NN + (size_t)(cc) * 32) * 4           \
            + ((u ^ (r_ & 7)) << 4);                                        \
        gload16(src_, &ring[slot_][i_ * 8][0]);                             \
      } }
    FILL(0); FILL(1); FILL(2);
    asm volatile("s_waitcnt vmcnt(8)" ::: "memory");   // slot 0 complete
    __builtin_amdgcn_sched_barrier(0);
    __builtin_amdgcn_s_barrier();
    #pragma unroll 1
    for (int c = 0; c < 64; ++c) {
      if (c < 61) {
        FILL(c + 3);
        asm volatile("s_waitcnt vmcnt(8)" ::: "memory");  // slot c+1 done
      } else if (c == 61) {
        asm volatile("s_waitcnt vmcnt(4)" ::: "memory");
      } else if (c == 62) {
        asm volatile("s_waitcnt vmcnt(0)" ::: "memory");
      }
      __builtin_amdgcn_sched_barrier(0);
      __builtin_amdgcn_s_barrier();
      asm volatile("" ::: "memory");
    }
#undef FILL
    return;
  }

  // ---------------- consumers (wv = 0,1) ----------------
  const int r = wv * 16 + l15;                  // row within block
  const float eL = el[b * NN + nb + r];
  const float* erp = er + b * NN;
  const unsigned char* hB = hS + (size_t)b * 32 * 16384;
  const int laneoff = l15 * 64 + ((kg ^ ((l >> 1) & 3)) * 16);
  const int u0 = (kg * 2) ^ (l15 & 7);          // swizzled 16B units
  const int u1 = (kg * 2 + 1) ^ (l15 & 7);
  const int aoff0 = r * 128 + u0 * 16;
  const int aoff1 = r * 128 + u1 * 16;

  f32x4 acc[4] = {{0.f,0.f,0.f,0.f},{0.f,0.f,0.f,0.f},
                  {0.f,0.f,0.f,0.f},{0.f,0.f,0.f,0.f}};
  float S = 0.f;

  __builtin_amdgcn_s_barrier();                 // matches producer prologue
  asm volatile("" ::: "memory");

  #pragma unroll 1
  for (int c = 0; c < 64; ++c) {
    // L2-only vmem loads: er + h-fragments (no HBM in this queue)
    float4 e0 = *(const float4*)(erp + c * 32 + kg * 8);
    float4 e1 = *(const float4*)(erp + c * 32 + kg * 8 + 4);
    bf16x8 BH[4], BL[4];
    {
      const unsigned char* p = hB + (size_t)c * 8192 + laneoff;
      #pragma unroll
      for (int ot = 0; ot < 4; ++ot) {
        BH[ot] = *(const bf16x8*)(p + ot * 1024);
        BL[ot] = *(const bf16x8*)(p + ot * 1024 + 4096);
      }
    }
    // adj from the ring (lgkm queue)
    const unsigned char* rs = &ring[c & (RING - 1)][0][0];
    int4 av0 = *(const int4*)(rs + aoff0);
    int4 av1 = *(const int4*)(rs + aoff1);

    int a0[8] = {av0.x, av0.y, av0.z, av0.w, av1.x, av1.y, av1.z, av1.w};
    float ee[8] = {e0.x, e0.y, e0.z, e0.w, e1.x, e1.y, e1.z, e1.w};

    bf16x8 afh, afl;
    #pragma unroll
    for (int j = 0; j < 8; ++j) {
      float e = eL + ee[j];
      e = fmaxf(e, ALPHA * e);
      float w = (a0[j] > 0) ? __expf(e) : 0.f;
      unsigned short h = f2bf(w);
      float wh = bf2f(h);
      unsigned short lo = f2bf(w - wh);
      afh[j] = (short)h;
      afl[j] = (short)lo;
      S += w;
    }

    #pragma unroll
    for (int ot = 0; ot < 4; ++ot) {
      acc[ot] = __builtin_amdgcn_mfma_f32_16x16x32_bf16(afh, BH[ot], acc[ot], 0, 0, 0);
      acc[ot] = __builtin_amdgcn_mfma_f32_16x16x32_bf16(afh, BL[ot], acc[ot], 0, 0, 0);
      acc[ot] = __builtin_amdgcn_mfma_f32_16x16x32_bf16(afl, BH[ot], acc[ot], 0, 0, 0);
    }

    __builtin_amdgcn_sched_barrier(0);
    __builtin_amdgcn_s_barrier();               // release slot, next ready
    asm volatile("" ::: "memory");
  }

  // epilogue: S reduce across kg copies, normalize, ELU, store
  S += __shfl_xor(S, 16);
  S += __shfl_xor(S, 32);
  float Sj[4];
  #pragma unroll
  for (int jj = 0; jj < 4; ++jj) Sj[jj] = __shfl(S, kg * 4 + jj);
  #pragma unroll
  for (int ot = 0; ot < 4; ++ot) {
    #pragma unroll
    for (int jj = 0; jj < 4; ++jj) {
      float v = acc[ot][jj] / Sj[jj];
      float rr = v > 0.f ? v : expm1f(v);
      out[((size_t)b * NN + nb + wv * 16 + kg * 4 + jj) * FOUT + ot * 16 + l15] = rr;
    }
  }
}

extern "C" void kernel_launch(void* const* d_in, const int* in_sizes, int n_in,
                              void* d_out, int out_size, void* d_ws, size_t ws_size,
                              hipStream_t stream) {
  const float* x   = (const float*)d_in[0];
  const int*   adj = (const int*)d_in[1];
  const float* W   = (const float*)d_in[2];
  const float* a   = (const float*)d_in[3];
  float* out = (float*)d_out;

  // ws layout: hS images (4MB) | el (64KB) | er (64KB)
  unsigned char* hS = (unsigned char*)d_ws;
  float* el = (float*)(hS + (size_t)BATCH * 32 * 16384);
  float* er = el + BATCH * NN;

  hipLaunchKernelGGL(k1_h, dim3(256), dim3(256), 0, stream, x, W, a, el, er, hS);
  hipLaunchKernelGGL(k2_attn, dim3(512), dim3(192), 0, stream, adj, hS, el, er, out);
}